// Round 2
// baseline (1487.029 us; speedup 1.0000x reference)
//
#include <hip/hip_runtime.h>
#include <stdint.h>
#include <math.h>

#define NW   12
#define DIM  4096
#define BSZ  1024

typedef short s16x8 __attribute__((ext_vector_type(8)));
typedef float f32x16 __attribute__((ext_vector_type(16)));

// ---------------------------------------------------------------------------
// fp32 -> bf16 (RNE) and hi/lo split helpers
__device__ __forceinline__ ushort f2bf(float x) {
    uint32_t u = __float_as_uint(x);
    uint32_t r = u + 0x7FFFu + ((u >> 16) & 1u);
    return (ushort)(r >> 16);
}
__device__ __forceinline__ float bf2f(ushort h) {
    return __uint_as_float(((uint32_t)h) << 16);
}
__device__ __forceinline__ void split2(float x, ushort& h, ushort& l) {
    h = f2bf(x);
    l = f2bf(x - bf2f(h));
}

// ---------------------------------------------------------------------------
// CNOT-ring permutation (reference translation): out[j] = in[perm12(j)]
__device__ __forceinline__ int perm12(int j) {
    int idx = j;
#pragma unroll
    for (int g = NW - 1; g >= 0; --g) {
        const int c = g;
        const int t = (g + 1) % NW;
        const int cbit = (idx >> (NW - 1 - c)) & 1;
        idx ^= cbit << (NW - 1 - t);
    }
    return idx;
}

__global__ void perm_kernel(int* __restrict__ invp) {
    const int j = blockIdx.x * blockDim.x + threadIdx.x;
    if (j < DIM) invp[perm12(j)] = j;   // invp = perm^-1 (bijection)
}

// ---------------------------------------------------------------------------
// Normalize each row of X and split into bf16 hi/lo (row-major [BSZ][DIM])
__global__ __launch_bounds__(256) void norm_split_kernel(const float* __restrict__ X,
                                                         ushort* __restrict__ Xh,
                                                         ushort* __restrict__ Xl) {
    const int b = blockIdx.x;
    const float* row = X + (size_t)b * DIM;
    float s = 0.f;
    for (int i = threadIdx.x; i < DIM; i += 256) {
        const float v = row[i];
        s += v * v;
    }
#pragma unroll
    for (int off = 32; off > 0; off >>= 1) s += __shfl_down(s, off, 64);
    __shared__ float ws4[4];
    if ((threadIdx.x & 63) == 0) ws4[threadIdx.x >> 6] = s;
    __syncthreads();
    const float inv = 1.0f / sqrtf(ws4[0] + ws4[1] + ws4[2] + ws4[3]);

    const float4* X4 = (const float4*)row;
#pragma unroll
    for (int j = 0; j < 4; ++j) {
        const int c = j * 256 + threadIdx.x;   // float4 index in row
        float4 v = X4[c];
        ushort h0, l0, h1, l1, h2, l2, h3, l3;
        split2(v.x * inv, h0, l0);
        split2(v.y * inv, h1, l1);
        split2(v.z * inv, h2, l2);
        split2(v.w * inv, h3, l3);
        uint2 hp, lp;
        hp.x = (uint)h0 | ((uint)h1 << 16); hp.y = (uint)h2 | ((uint)h3 << 16);
        lp.x = (uint)l0 | ((uint)l1 << 16); lp.y = (uint)l2 | ((uint)l3 << 16);
        *(uint2*)(Xh + (size_t)b * DIM + c * 4) = hp;
        *(uint2*)(Xl + (size_t)b * DIM + c * 4) = lp;
    }
}

// ---------------------------------------------------------------------------
// Stage 1:  y = U * xhat  (complex output from real input), column-permuted
// split-bf16 store.   C[b,i] = sum_j X[b,j] * U[i,j]   (A*B^T, both row-major)
// Block: BM=128 (batch) x BN=64 (i), BK=32. 4 waves, wave-tile 64x32,
// 2 m-frags of 32x32 MFMA.
__global__ __launch_bounds__(256, 2) void stage1(
    const ushort* __restrict__ Xh, const ushort* __restrict__ Xl,
    const float* __restrict__ Ure, const float* __restrict__ Uim,
    const int* __restrict__ invp,
    ushort* __restrict__ Srh, ushort* __restrict__ Srl,
    ushort* __restrict__ Sih, ushort* __restrict__ Sil) {
    __shared__ short Ah[4][128][8], Al[4][128][8];      // X tile  [kb][row][e]
    __shared__ short Bh0[4][64][8], Bl0[4][64][8];      // Ure tile
    __shared__ short Bh1[4][64][8], Bl1[4][64][8];      // Uim tile

    const int t    = threadIdx.x;
    const int lane = t & 63;
    const int w    = t >> 6;
    const int wm   = w >> 1, wn = w & 1;
    const int bn   = blockIdx.x * 64;    // i-block   (x => same-N co-XCD)
    const int bm   = blockIdx.y * 128;   // batch-block

    uint4  pAh[2], pAl[2];
    float4 pBr[2], pBi[2];

#define S1_LOAD(k0)                                                         \
    {                                                                       \
        _Pragma("unroll") for (int j = 0; j < 2; ++j) {                     \
            const int ch = j * 256 + t;                                     \
            const int ar = ch >> 2, akb = ch & 3;                           \
            const size_t ga = (size_t)(bm + ar) * DIM + (k0) + akb * 8;     \
            pAh[j] = *(const uint4*)(Xh + ga);                              \
            pAl[j] = *(const uint4*)(Xl + ga);                              \
            const int br = ch >> 3, fc = ch & 7;                            \
            const size_t gb = (size_t)(bn + br) * DIM + (k0) + fc * 4;      \
            pBr[j] = *(const float4*)(Ure + gb);                            \
            pBi[j] = *(const float4*)(Uim + gb);                            \
        }                                                                   \
    }

    f32x16 accr[2], acci[2];
#pragma unroll
    for (int mi = 0; mi < 2; ++mi)
#pragma unroll
        for (int e = 0; e < 16; ++e) { accr[mi][e] = 0.f; acci[mi][e] = 0.f; }

    S1_LOAD(0);

    for (int k0 = 0; k0 < DIM; k0 += 32) {
        __syncthreads();
#pragma unroll
        for (int j = 0; j < 2; ++j) {
            const int ch = j * 256 + t;
            const int ar = ch >> 2, akb = ch & 3;
            *(uint4*)&Ah[akb][ar][0] = pAh[j];
            *(uint4*)&Al[akb][ar][0] = pAl[j];
            const int br = ch >> 3, fc = ch & 7;
            const int bkb = fc >> 1, bo = (fc & 1) * 4;
            ushort h0, l0, h1, l1, h2, l2, h3, l3;
            split2(pBr[j].x, h0, l0); split2(pBr[j].y, h1, l1);
            split2(pBr[j].z, h2, l2); split2(pBr[j].w, h3, l3);
            *(uint2*)&Bh0[bkb][br][bo] = make_uint2((uint)h0 | ((uint)h1 << 16), (uint)h2 | ((uint)h3 << 16));
            *(uint2*)&Bl0[bkb][br][bo] = make_uint2((uint)l0 | ((uint)l1 << 16), (uint)l2 | ((uint)l3 << 16));
            split2(pBi[j].x, h0, l0); split2(pBi[j].y, h1, l1);
            split2(pBi[j].z, h2, l2); split2(pBi[j].w, h3, l3);
            *(uint2*)&Bh1[bkb][br][bo] = make_uint2((uint)h0 | ((uint)h1 << 16), (uint)h2 | ((uint)h3 << 16));
            *(uint2*)&Bl1[bkb][br][bo] = make_uint2((uint)l0 | ((uint)l1 << 16), (uint)l2 | ((uint)l3 << 16));
        }
        __syncthreads();
        if (k0 + 32 < DIM) S1_LOAD(k0 + 32);

#pragma unroll
        for (int ks = 0; ks < 2; ++ks) {
            const int kb = ks * 2 + (lane >> 5);
            const int r  = lane & 31;
            const s16x8 bh0 = *(const s16x8*)&Bh0[kb][wn * 32 + r][0];
            const s16x8 bl0 = *(const s16x8*)&Bl0[kb][wn * 32 + r][0];
            const s16x8 bh1 = *(const s16x8*)&Bh1[kb][wn * 32 + r][0];
            const s16x8 bl1 = *(const s16x8*)&Bl1[kb][wn * 32 + r][0];
#pragma unroll
            for (int mi = 0; mi < 2; ++mi) {
                const s16x8 ah = *(const s16x8*)&Ah[kb][wm * 64 + mi * 32 + r][0];
                const s16x8 al = *(const s16x8*)&Al[kb][wm * 64 + mi * 32 + r][0];
                accr[mi] = __builtin_amdgcn_mfma_f32_32x32x16_bf16(ah, bh0, accr[mi], 0, 0, 0);
                accr[mi] = __builtin_amdgcn_mfma_f32_32x32x16_bf16(al, bh0, accr[mi], 0, 0, 0);
                accr[mi] = __builtin_amdgcn_mfma_f32_32x32x16_bf16(ah, bl0, accr[mi], 0, 0, 0);
                acci[mi] = __builtin_amdgcn_mfma_f32_32x32x16_bf16(ah, bh1, acci[mi], 0, 0, 0);
                acci[mi] = __builtin_amdgcn_mfma_f32_32x32x16_bf16(al, bh1, acci[mi], 0, 0, 0);
                acci[mi] = __builtin_amdgcn_mfma_f32_32x32x16_bf16(ah, bl1, acci[mi], 0, 0, 0);
            }
        }
    }

    // Epilogue: split to bf16 hi/lo, scatter to permuted column invp[i].
    const int col = bn + wn * 32 + (lane & 31);
    const int pc  = invp[col];
#pragma unroll
    for (int mi = 0; mi < 2; ++mi) {
#pragma unroll
        for (int reg = 0; reg < 16; ++reg) {
            const int rl   = (reg & 3) + 8 * (reg >> 2) + 4 * (lane >> 5);
            const int grow = bm + wm * 64 + mi * 32 + rl;
            const size_t o = (size_t)grow * DIM + pc;
            ushort h, l;
            split2(accr[mi][reg], h, l);
            Srh[o] = h; Srl[o] = l;
            split2(acci[mi][reg], h, l);
            Sih[o] = h; Sil[o] = l;
        }
    }
#undef S1_LOAD
}

// ---------------------------------------------------------------------------
// Stage 2:  out = | U1 * s' |   (full complex GEMM, 12 split-products)
__global__ __launch_bounds__(256, 2) void stage2(
    const ushort* __restrict__ Srh, const ushort* __restrict__ Srl,
    const ushort* __restrict__ Sih, const ushort* __restrict__ Sil,
    const float* __restrict__ U1re, const float* __restrict__ U1im,
    float* __restrict__ Out) {
    __shared__ short Arh[4][128][8], Arl[4][128][8];    // state re tiles
    __shared__ short Aih[4][128][8], Ail[4][128][8];    // state im tiles
    __shared__ short Bh0[4][64][8], Bl0[4][64][8];      // U1re tile
    __shared__ short Bh1[4][64][8], Bl1[4][64][8];      // U1im tile

    const int t    = threadIdx.x;
    const int lane = t & 63;
    const int w    = t >> 6;
    const int wm   = w >> 1, wn = w & 1;
    const int bn   = blockIdx.x * 64;
    const int bm   = blockIdx.y * 128;

    uint4  pRh[2], pRl[2], pIh[2], pIl[2];
    float4 pBr[2], pBi[2];

#define S2_LOAD(k0)                                                         \
    {                                                                       \
        _Pragma("unroll") for (int j = 0; j < 2; ++j) {                     \
            const int ch = j * 256 + t;                                     \
            const int ar = ch >> 2, akb = ch & 3;                           \
            const size_t ga = (size_t)(bm + ar) * DIM + (k0) + akb * 8;     \
            pRh[j] = *(const uint4*)(Srh + ga);                             \
            pRl[j] = *(const uint4*)(Srl + ga);                             \
            pIh[j] = *(const uint4*)(Sih + ga);                             \
            pIl[j] = *(const uint4*)(Sil + ga);                             \
            const int br = ch >> 3, fc = ch & 7;                            \
            const size_t gb = (size_t)(bn + br) * DIM + (k0) + fc * 4;      \
            pBr[j] = *(const float4*)(U1re + gb);                           \
            pBi[j] = *(const float4*)(U1im + gb);                           \
        }                                                                   \
    }

    f32x16 accr[2], acci[2];
#pragma unroll
    for (int mi = 0; mi < 2; ++mi)
#pragma unroll
        for (int e = 0; e < 16; ++e) { accr[mi][e] = 0.f; acci[mi][e] = 0.f; }

    S2_LOAD(0);

    for (int k0 = 0; k0 < DIM; k0 += 32) {
        __syncthreads();
#pragma unroll
        for (int j = 0; j < 2; ++j) {
            const int ch = j * 256 + t;
            const int ar = ch >> 2, akb = ch & 3;
            *(uint4*)&Arh[akb][ar][0] = pRh[j];
            *(uint4*)&Arl[akb][ar][0] = pRl[j];
            *(uint4*)&Aih[akb][ar][0] = pIh[j];
            *(uint4*)&Ail[akb][ar][0] = pIl[j];
            const int br = ch >> 3, fc = ch & 7;
            const int bkb = fc >> 1, bo = (fc & 1) * 4;
            ushort h0, l0, h1, l1, h2, l2, h3, l3;
            split2(pBr[j].x, h0, l0); split2(pBr[j].y, h1, l1);
            split2(pBr[j].z, h2, l2); split2(pBr[j].w, h3, l3);
            *(uint2*)&Bh0[bkb][br][bo] = make_uint2((uint)h0 | ((uint)h1 << 16), (uint)h2 | ((uint)h3 << 16));
            *(uint2*)&Bl0[bkb][br][bo] = make_uint2((uint)l0 | ((uint)l1 << 16), (uint)l2 | ((uint)l3 << 16));
            split2(pBi[j].x, h0, l0); split2(pBi[j].y, h1, l1);
            split2(pBi[j].z, h2, l2); split2(pBi[j].w, h3, l3);
            *(uint2*)&Bh1[bkb][br][bo] = make_uint2((uint)h0 | ((uint)h1 << 16), (uint)h2 | ((uint)h3 << 16));
            *(uint2*)&Bl1[bkb][br][bo] = make_uint2((uint)l0 | ((uint)l1 << 16), (uint)l2 | ((uint)l3 << 16));
        }
        __syncthreads();
        if (k0 + 32 < DIM) S2_LOAD(k0 + 32);

#pragma unroll
        for (int ks = 0; ks < 2; ++ks) {
            const int kb = ks * 2 + (lane >> 5);
            const int r  = lane & 31;
            const s16x8 urh = *(const s16x8*)&Bh0[kb][wn * 32 + r][0];
            const s16x8 url = *(const s16x8*)&Bl0[kb][wn * 32 + r][0];
            const s16x8 uih = *(const s16x8*)&Bh1[kb][wn * 32 + r][0];
            const s16x8 uil = *(const s16x8*)&Bl1[kb][wn * 32 + r][0];
            const s16x8 nuih = uih ^ (short)0x8000;   // -uih (sign-bit flip)
            const s16x8 nuil = uil ^ (short)0x8000;
#pragma unroll
            for (int mi = 0; mi < 2; ++mi) {
                const int arow = wm * 64 + mi * 32 + r;
                const s16x8 srh = *(const s16x8*)&Arh[kb][arow][0];
                const s16x8 srl = *(const s16x8*)&Arl[kb][arow][0];
                const s16x8 sih = *(const s16x8*)&Aih[kb][arow][0];
                const s16x8 sil = *(const s16x8*)&Ail[kb][arow][0];
                // re: sr*ur - si*ui
                accr[mi] = __builtin_amdgcn_mfma_f32_32x32x16_bf16(srh, urh,  accr[mi], 0, 0, 0);
                accr[mi] = __builtin_amdgcn_mfma_f32_32x32x16_bf16(srl, urh,  accr[mi], 0, 0, 0);
                accr[mi] = __builtin_amdgcn_mfma_f32_32x32x16_bf16(srh, url,  accr[mi], 0, 0, 0);
                accr[mi] = __builtin_amdgcn_mfma_f32_32x32x16_bf16(sih, nuih, accr[mi], 0, 0, 0);
                accr[mi] = __builtin_amdgcn_mfma_f32_32x32x16_bf16(sil, nuih, accr[mi], 0, 0, 0);
                accr[mi] = __builtin_amdgcn_mfma_f32_32x32x16_bf16(sih, nuil, accr[mi], 0, 0, 0);
                // im: sr*ui + si*ur
                acci[mi] = __builtin_amdgcn_mfma_f32_32x32x16_bf16(srh, uih,  acci[mi], 0, 0, 0);
                acci[mi] = __builtin_amdgcn_mfma_f32_32x32x16_bf16(srl, uih,  acci[mi], 0, 0, 0);
                acci[mi] = __builtin_amdgcn_mfma_f32_32x32x16_bf16(srh, uil,  acci[mi], 0, 0, 0);
                acci[mi] = __builtin_amdgcn_mfma_f32_32x32x16_bf16(sih, urh,  acci[mi], 0, 0, 0);
                acci[mi] = __builtin_amdgcn_mfma_f32_32x32x16_bf16(sil, urh,  acci[mi], 0, 0, 0);
                acci[mi] = __builtin_amdgcn_mfma_f32_32x32x16_bf16(sih, url,  acci[mi], 0, 0, 0);
            }
        }
    }

    const int col = bn + wn * 32 + (lane & 31);
#pragma unroll
    for (int mi = 0; mi < 2; ++mi) {
#pragma unroll
        for (int reg = 0; reg < 16; ++reg) {
            const int rl   = (reg & 3) + 8 * (reg >> 2) + 4 * (lane >> 5);
            const int grow = bm + wm * 64 + mi * 32 + rl;
            const float vr = accr[mi][reg], vi = acci[mi][reg];
            Out[(size_t)grow * DIM + col] = sqrtf(vr * vr + vi * vi);
        }
    }
#undef S2_LOAD
}

// ---------------------------------------------------------------------------
extern "C" void kernel_launch(void* const* d_in, const int* in_sizes, int n_in,
                              void* d_out, int out_size, void* d_ws, size_t ws_size,
                              hipStream_t stream) {
    const float* X    = (const float*)d_in[0];
    const float* Ure  = (const float*)d_in[1];
    const float* Uim  = (const float*)d_in[2];
    const float* U1re = (const float*)d_in[3];
    const float* U1im = (const float*)d_in[4];
    float* Out = (float*)d_out;

    char* w = (char*)d_ws;
    const size_t MAT = (size_t)BSZ * DIM;          // elements per bf16 matrix
    int*    invp = (int*)w;                        // 16 KB
    ushort* Xh   = (ushort*)(w + (1 << 14));
    ushort* Xl   = Xh + MAT;
    ushort* Srh  = Xl + MAT;
    ushort* Srl  = Srh + MAT;
    ushort* Sih  = Srl + MAT;
    ushort* Sil  = Sih + MAT;                      // total 16KB + 48 MB

    perm_kernel<<<DIM / 256, 256, 0, stream>>>(invp);
    norm_split_kernel<<<BSZ, 256, 0, stream>>>(X, Xh, Xl);

    dim3 grid(DIM / 64, BSZ / 128);   // (64, 8): x=N-block => same-N co-XCD
    stage1<<<grid, 256, 0, stream>>>(Xh, Xl, Ure, Uim, invp, Srh, Srl, Sih, Sil);
    stage2<<<grid, 256, 0, stream>>>(Srh, Srl, Sih, Sil, U1re, U1im, Out);
}

// Round 3
// 1485.264 us; speedup vs baseline: 1.0012x; 1.0012x over previous
//
#include <hip/hip_runtime.h>
#include <stdint.h>
#include <math.h>

#define NW   12
#define DIM  4096
#define BSZ  1024

typedef short s16x8 __attribute__((ext_vector_type(8)));
typedef float f32x16 __attribute__((ext_vector_type(16)));

// ---------------------------------------------------------------------------
__device__ __forceinline__ ushort f2bf(float x) {
    uint32_t u = __float_as_uint(x);
    uint32_t r = u + 0x7FFFu + ((u >> 16) & 1u);
    return (ushort)(r >> 16);
}
__device__ __forceinline__ float bf2f(ushort h) {
    return __uint_as_float(((uint32_t)h) << 16);
}
__device__ __forceinline__ void split2(float x, ushort& h, ushort& l) {
    h = f2bf(x);
    l = f2bf(x - bf2f(h));
}
__device__ __forceinline__ uint pack2(ushort a, ushort b) {
    return (uint)a | ((uint)b << 16);
}

// global_load_lds, 16B per lane; LDS dest = uniform base + lane*16
#define GL16(G, L)                                                            \
    __builtin_amdgcn_global_load_lds(                                         \
        (const __attribute__((address_space(1))) unsigned int*)(const void*)(G), \
        (__attribute__((address_space(3))) unsigned int*)(void*)(L), 16, 0, 0)

// ---------------------------------------------------------------------------
// CNOT-ring permutation (reference translation): out[j] = in[perm12(j)]
__device__ __forceinline__ int perm12(int j) {
    int idx = j;
#pragma unroll
    for (int g = NW - 1; g >= 0; --g) {
        const int c = g;
        const int t = (g + 1) % NW;
        const int cbit = (idx >> (NW - 1 - c)) & 1;
        idx ^= cbit << (NW - 1 - t);
    }
    return idx;
}

__global__ void perm_kernel(int* __restrict__ invp) {
    const int j = blockIdx.x * blockDim.x + threadIdx.x;
    if (j < DIM) invp[perm12(j)] = j;   // invp = perm^-1 (bijection)
}

// ---------------------------------------------------------------------------
// Normalize each row of X and split into bf16 hi/lo
__global__ __launch_bounds__(256) void norm_split_kernel(const float* __restrict__ X,
                                                         ushort* __restrict__ Xh,
                                                         ushort* __restrict__ Xl) {
    const int b = blockIdx.x;
    const float* row = X + (size_t)b * DIM;
    float s = 0.f;
    for (int i = threadIdx.x; i < DIM; i += 256) {
        const float v = row[i];
        s += v * v;
    }
#pragma unroll
    for (int off = 32; off > 0; off >>= 1) s += __shfl_down(s, off, 64);
    __shared__ float ws4[4];
    if ((threadIdx.x & 63) == 0) ws4[threadIdx.x >> 6] = s;
    __syncthreads();
    const float inv = 1.0f / sqrtf(ws4[0] + ws4[1] + ws4[2] + ws4[3]);

    const float4* X4 = (const float4*)row;
#pragma unroll
    for (int j = 0; j < 4; ++j) {
        const int c = j * 256 + threadIdx.x;
        float4 v = X4[c];
        ushort h0, l0, h1, l1, h2, l2, h3, l3;
        split2(v.x * inv, h0, l0);
        split2(v.y * inv, h1, l1);
        split2(v.z * inv, h2, l2);
        split2(v.w * inv, h3, l3);
        *(uint2*)(Xh + (size_t)b * DIM + c * 4) = make_uint2(pack2(h0, h1), pack2(h2, h3));
        *(uint2*)(Xl + (size_t)b * DIM + c * 4) = make_uint2(pack2(l0, l1), pack2(l2, l3));
    }
}

// ---------------------------------------------------------------------------
// Pre-split a complex fp32 matrix into 4 bf16 matrices (hi/lo of re/im).
// PERM: gather columns through gidx (folds the CNOT permutation into U1).
template <bool PERM>
__global__ __launch_bounds__(256) void presplit(
    const float* __restrict__ Re, const float* __restrict__ Im,
    const int* __restrict__ gidx,
    ushort* __restrict__ Rh, ushort* __restrict__ Rl,
    ushort* __restrict__ Ih, ushort* __restrict__ Il) {
    const size_t base = (size_t)blockIdx.x * DIM;
#pragma unroll
    for (int c = 0; c < 4; ++c) {
        const int col = c * 1024 + threadIdx.x * 4;
        float vr[4], vi[4];
        if constexpr (PERM) {
            const int4 g = *(const int4*)&gidx[col];
            vr[0] = Re[base + g.x]; vr[1] = Re[base + g.y];
            vr[2] = Re[base + g.z]; vr[3] = Re[base + g.w];
            vi[0] = Im[base + g.x]; vi[1] = Im[base + g.y];
            vi[2] = Im[base + g.z]; vi[3] = Im[base + g.w];
        } else {
            const float4 a = *(const float4*)&Re[base + col];
            const float4 b = *(const float4*)&Im[base + col];
            vr[0] = a.x; vr[1] = a.y; vr[2] = a.z; vr[3] = a.w;
            vi[0] = b.x; vi[1] = b.y; vi[2] = b.z; vi[3] = b.w;
        }
        ushort h0, l0, h1, l1, h2, l2, h3, l3;
        split2(vr[0], h0, l0); split2(vr[1], h1, l1);
        split2(vr[2], h2, l2); split2(vr[3], h3, l3);
        *(uint2*)&Rh[base + col] = make_uint2(pack2(h0, h1), pack2(h2, h3));
        *(uint2*)&Rl[base + col] = make_uint2(pack2(l0, l1), pack2(l2, l3));
        split2(vi[0], h0, l0); split2(vi[1], h1, l1);
        split2(vi[2], h2, l2); split2(vi[3], h3, l3);
        *(uint2*)&Ih[base + col] = make_uint2(pack2(h0, h1), pack2(h2, h3));
        *(uint2*)&Il[base + col] = make_uint2(pack2(l0, l1), pack2(l2, l3));
    }
}

// ---------------------------------------------------------------------------
// Stage 1 (gload_lds path): S = U * xhat, stored contiguous bf16 hi/lo.
// Block 128(batch) x 64(i), BK=32, 4 waves, wave-tile 64x32 (2 m-frags).
__global__ __launch_bounds__(256, 2) void stage1_gl(
    const ushort* __restrict__ Xh, const ushort* __restrict__ Xl,
    const ushort* __restrict__ Urh, const ushort* __restrict__ Url,
    const ushort* __restrict__ Uih, const ushort* __restrict__ Uil,
    ushort* __restrict__ Srh, ushort* __restrict__ Srl,
    ushort* __restrict__ Sih, ushort* __restrict__ Sil) {
    __shared__ short Ab[2][4][128][8];   // [mat][kb][row][e]  16KB
    __shared__ short Bb[4][4][64][8];    // 16KB

    const int t = threadIdx.x, lane = t & 63, w = t >> 6;
    const int wm = w >> 1, wn = w & 1;
    const int bm = blockIdx.x * 128;   // batch block (8)  -> XCD = panel
    const int bn = blockIdx.y * 64;    // i block (64)

    const ushort* Amat[2] = {Xh, Xl};
    const ushort* Bmat[4] = {Urh, Url, Uih, Uil};
    const ushort* gsrc[8];
    short* ldst[8];
#pragma unroll
    for (int q = 0; q < 8; ++q) {
        const int g = w * 8 + q;
        if (g < 16) {   // A instrs: mat(2) x kb(4) x half(2)
            const int mat = g >> 3, kb = (g >> 1) & 3, half = g & 1;
            gsrc[q] = Amat[mat] + (size_t)(bm + half * 64 + lane) * DIM + kb * 8;
            ldst[q] = &Ab[mat][kb][half * 64][0];
        } else {        // B instrs: mat(4) x kb(4)
            const int h = g - 16, mat = h >> 2, kb = h & 3;
            gsrc[q] = Bmat[mat] + (size_t)(bn + lane) * DIM + kb * 8;
            ldst[q] = &Bb[mat][kb][0][0];
        }
    }

    f32x16 accr[2], acci[2];
#pragma unroll
    for (int mi = 0; mi < 2; ++mi)
#pragma unroll
        for (int e = 0; e < 16; ++e) { accr[mi][e] = 0.f; acci[mi][e] = 0.f; }

    for (int k0 = 0; k0 < DIM; k0 += 32) {
#pragma unroll
        for (int q = 0; q < 8; ++q) GL16(gsrc[q] + k0, ldst[q]);
        __syncthreads();   // drains vmcnt before barrier (compiler-inserted)
#pragma unroll
        for (int ks = 0; ks < 2; ++ks) {
            const int kb = ks * 2 + (lane >> 5);
            const int r  = lane & 31;
            const s16x8 urh = *(const s16x8*)&Bb[0][kb][wn * 32 + r][0];
            const s16x8 url = *(const s16x8*)&Bb[1][kb][wn * 32 + r][0];
            const s16x8 uih = *(const s16x8*)&Bb[2][kb][wn * 32 + r][0];
            const s16x8 uil = *(const s16x8*)&Bb[3][kb][wn * 32 + r][0];
#pragma unroll
            for (int mi = 0; mi < 2; ++mi) {
                const int ar = wm * 64 + mi * 32 + r;
                const s16x8 ah = *(const s16x8*)&Ab[0][kb][ar][0];
                const s16x8 al = *(const s16x8*)&Ab[1][kb][ar][0];
                accr[mi] = __builtin_amdgcn_mfma_f32_32x32x16_bf16(ah, urh, accr[mi], 0, 0, 0);
                accr[mi] = __builtin_amdgcn_mfma_f32_32x32x16_bf16(al, urh, accr[mi], 0, 0, 0);
                accr[mi] = __builtin_amdgcn_mfma_f32_32x32x16_bf16(ah, url, accr[mi], 0, 0, 0);
                acci[mi] = __builtin_amdgcn_mfma_f32_32x32x16_bf16(ah, uih, acci[mi], 0, 0, 0);
                acci[mi] = __builtin_amdgcn_mfma_f32_32x32x16_bf16(al, uih, acci[mi], 0, 0, 0);
                acci[mi] = __builtin_amdgcn_mfma_f32_32x32x16_bf16(ah, uil, acci[mi], 0, 0, 0);
            }
        }
        __syncthreads();
    }

    // Contiguous (unpermuted) bf16 hi/lo store of S.
    const int col = bn + wn * 32 + (lane & 31);
#pragma unroll
    for (int mi = 0; mi < 2; ++mi) {
#pragma unroll
        for (int reg = 0; reg < 16; ++reg) {
            const int rl  = (reg & 3) + 8 * (reg >> 2) + 4 * (lane >> 5);
            const int row = bm + wm * 64 + mi * 32 + rl;
            const size_t o = (size_t)row * DIM + col;
            ushort h, l;
            split2(accr[mi][reg], h, l);
            Srh[o] = h; Srl[o] = l;
            split2(acci[mi][reg], h, l);
            Sih[o] = h; Sil[o] = l;
        }
    }
}

// ---------------------------------------------------------------------------
// Stage 2 (gload_lds path): out = | V * S |, V = column-permuted U1 (pre-split).
__global__ __launch_bounds__(256, 2) void stage2_gl(
    const ushort* __restrict__ Srh, const ushort* __restrict__ Srl,
    const ushort* __restrict__ Sih, const ushort* __restrict__ Sil,
    const ushort* __restrict__ Vrh, const ushort* __restrict__ Vrl,
    const ushort* __restrict__ Vih, const ushort* __restrict__ Vil,
    float* __restrict__ Out) {
    __shared__ short Ab[4][4][128][8];   // 32KB
    __shared__ short Bb[4][4][64][8];    // 16KB

    const int t = threadIdx.x, lane = t & 63, w = t >> 6;
    const int wm = w >> 1, wn = w & 1;
    const int bm = blockIdx.x * 128;
    const int bn = blockIdx.y * 64;

    const ushort* Amat[4] = {Srh, Srl, Sih, Sil};
    const ushort* Bmat[4] = {Vrh, Vrl, Vih, Vil};
    const ushort* gsrc[12];
    short* ldst[12];
#pragma unroll
    for (int q = 0; q < 12; ++q) {
        const int g = w * 12 + q;
        if (g < 32) {   // A: mat(4) x kb(4) x half(2)
            const int mat = g >> 3, kb = (g >> 1) & 3, half = g & 1;
            gsrc[q] = Amat[mat] + (size_t)(bm + half * 64 + lane) * DIM + kb * 8;
            ldst[q] = &Ab[mat][kb][half * 64][0];
        } else {        // B: mat(4) x kb(4)
            const int h = g - 32, mat = h >> 2, kb = h & 3;
            gsrc[q] = Bmat[mat] + (size_t)(bn + lane) * DIM + kb * 8;
            ldst[q] = &Bb[mat][kb][0][0];
        }
    }

    f32x16 accr[2], acci[2];
#pragma unroll
    for (int mi = 0; mi < 2; ++mi)
#pragma unroll
        for (int e = 0; e < 16; ++e) { accr[mi][e] = 0.f; acci[mi][e] = 0.f; }

    for (int k0 = 0; k0 < DIM; k0 += 32) {
#pragma unroll
        for (int q = 0; q < 12; ++q) GL16(gsrc[q] + k0, ldst[q]);
        __syncthreads();
#pragma unroll
        for (int ks = 0; ks < 2; ++ks) {
            const int kb = ks * 2 + (lane >> 5);
            const int r  = lane & 31;
            const s16x8 urh = *(const s16x8*)&Bb[0][kb][wn * 32 + r][0];
            const s16x8 url = *(const s16x8*)&Bb[1][kb][wn * 32 + r][0];
            const s16x8 uih = *(const s16x8*)&Bb[2][kb][wn * 32 + r][0];
            const s16x8 uil = *(const s16x8*)&Bb[3][kb][wn * 32 + r][0];
            const s16x8 nuih = uih ^ (short)0x8000;
            const s16x8 nuil = uil ^ (short)0x8000;
#pragma unroll
            for (int mi = 0; mi < 2; ++mi) {
                const int ar = wm * 64 + mi * 32 + r;
                const s16x8 srh = *(const s16x8*)&Ab[0][kb][ar][0];
                const s16x8 srl = *(const s16x8*)&Ab[1][kb][ar][0];
                const s16x8 sih = *(const s16x8*)&Ab[2][kb][ar][0];
                const s16x8 sil = *(const s16x8*)&Ab[3][kb][ar][0];
                accr[mi] = __builtin_amdgcn_mfma_f32_32x32x16_bf16(srh, urh,  accr[mi], 0, 0, 0);
                accr[mi] = __builtin_amdgcn_mfma_f32_32x32x16_bf16(srl, urh,  accr[mi], 0, 0, 0);
                accr[mi] = __builtin_amdgcn_mfma_f32_32x32x16_bf16(srh, url,  accr[mi], 0, 0, 0);
                accr[mi] = __builtin_amdgcn_mfma_f32_32x32x16_bf16(sih, nuih, accr[mi], 0, 0, 0);
                accr[mi] = __builtin_amdgcn_mfma_f32_32x32x16_bf16(sil, nuih, accr[mi], 0, 0, 0);
                accr[mi] = __builtin_amdgcn_mfma_f32_32x32x16_bf16(sih, nuil, accr[mi], 0, 0, 0);
                acci[mi] = __builtin_amdgcn_mfma_f32_32x32x16_bf16(srh, uih,  acci[mi], 0, 0, 0);
                acci[mi] = __builtin_amdgcn_mfma_f32_32x32x16_bf16(srl, uih,  acci[mi], 0, 0, 0);
                acci[mi] = __builtin_amdgcn_mfma_f32_32x32x16_bf16(srh, uil,  acci[mi], 0, 0, 0);
                acci[mi] = __builtin_amdgcn_mfma_f32_32x32x16_bf16(sih, urh,  acci[mi], 0, 0, 0);
                acci[mi] = __builtin_amdgcn_mfma_f32_32x32x16_bf16(sil, urh,  acci[mi], 0, 0, 0);
                acci[mi] = __builtin_amdgcn_mfma_f32_32x32x16_bf16(sih, url,  acci[mi], 0, 0, 0);
            }
        }
        __syncthreads();
    }

    const int col = bn + wn * 32 + (lane & 31);
#pragma unroll
    for (int mi = 0; mi < 2; ++mi) {
#pragma unroll
        for (int reg = 0; reg < 16; ++reg) {
            const int rl  = (reg & 3) + 8 * (reg >> 2) + 4 * (lane >> 5);
            const int row = bm + wm * 64 + mi * 32 + rl;
            const float vr = accr[mi][reg], vi = acci[mi][reg];
            Out[(size_t)row * DIM + col] = sqrtf(vr * vr + vi * vi);
        }
    }
}

// ===========================================================================
// Fallback path (verbatim round-1 kernels; used when ws_size is too small)
// ===========================================================================
__global__ __launch_bounds__(256, 2) void stage1_fb(
    const ushort* __restrict__ Xh, const ushort* __restrict__ Xl,
    const float* __restrict__ Ure, const float* __restrict__ Uim,
    const int* __restrict__ invp,
    ushort* __restrict__ Srh, ushort* __restrict__ Srl,
    ushort* __restrict__ Sih, ushort* __restrict__ Sil) {
    __shared__ short Ah[4][128][8], Al[4][128][8];
    __shared__ short Bh0[4][64][8], Bl0[4][64][8];
    __shared__ short Bh1[4][64][8], Bl1[4][64][8];

    const int t = threadIdx.x;
    const int lane = t & 63;
    const int w = t >> 6;
    const int wm = w >> 1, wn = w & 1;
    const int bn = blockIdx.x * 64;
    const int bm = blockIdx.y * 128;

    uint4 pAh[2], pAl[2];
    float4 pBr[2], pBi[2];

#define S1_LOAD(k0)                                                         \
    {                                                                       \
        _Pragma("unroll") for (int j = 0; j < 2; ++j) {                     \
            const int ch = j * 256 + t;                                     \
            const int ar = ch >> 2, akb = ch & 3;                           \
            const size_t ga = (size_t)(bm + ar) * DIM + (k0) + akb * 8;     \
            pAh[j] = *(const uint4*)(Xh + ga);                              \
            pAl[j] = *(const uint4*)(Xl + ga);                              \
            const int br = ch >> 3, fc = ch & 7;                            \
            const size_t gb = (size_t)(bn + br) * DIM + (k0) + fc * 4;      \
            pBr[j] = *(const float4*)(Ure + gb);                            \
            pBi[j] = *(const float4*)(Uim + gb);                            \
        }                                                                   \
    }

    f32x16 accr[2], acci[2];
#pragma unroll
    for (int mi = 0; mi < 2; ++mi)
#pragma unroll
        for (int e = 0; e < 16; ++e) { accr[mi][e] = 0.f; acci[mi][e] = 0.f; }

    S1_LOAD(0);

    for (int k0 = 0; k0 < DIM; k0 += 32) {
        __syncthreads();
#pragma unroll
        for (int j = 0; j < 2; ++j) {
            const int ch = j * 256 + t;
            const int ar = ch >> 2, akb = ch & 3;
            *(uint4*)&Ah[akb][ar][0] = pAh[j];
            *(uint4*)&Al[akb][ar][0] = pAl[j];
            const int br = ch >> 3, fc = ch & 7;
            const int bkb = fc >> 1, bo = (fc & 1) * 4;
            ushort h0, l0, h1, l1, h2, l2, h3, l3;
            split2(pBr[j].x, h0, l0); split2(pBr[j].y, h1, l1);
            split2(pBr[j].z, h2, l2); split2(pBr[j].w, h3, l3);
            *(uint2*)&Bh0[bkb][br][bo] = make_uint2(pack2(h0, h1), pack2(h2, h3));
            *(uint2*)&Bl0[bkb][br][bo] = make_uint2(pack2(l0, l1), pack2(l2, l3));
            split2(pBi[j].x, h0, l0); split2(pBi[j].y, h1, l1);
            split2(pBi[j].z, h2, l2); split2(pBi[j].w, h3, l3);
            *(uint2*)&Bh1[bkb][br][bo] = make_uint2(pack2(h0, h1), pack2(h2, h3));
            *(uint2*)&Bl1[bkb][br][bo] = make_uint2(pack2(l0, l1), pack2(l2, l3));
        }
        __syncthreads();
        if (k0 + 32 < DIM) S1_LOAD(k0 + 32);

#pragma unroll
        for (int ks = 0; ks < 2; ++ks) {
            const int kb = ks * 2 + (lane >> 5);
            const int r  = lane & 31;
            const s16x8 bh0 = *(const s16x8*)&Bh0[kb][wn * 32 + r][0];
            const s16x8 bl0 = *(const s16x8*)&Bl0[kb][wn * 32 + r][0];
            const s16x8 bh1 = *(const s16x8*)&Bh1[kb][wn * 32 + r][0];
            const s16x8 bl1 = *(const s16x8*)&Bl1[kb][wn * 32 + r][0];
#pragma unroll
            for (int mi = 0; mi < 2; ++mi) {
                const s16x8 ah = *(const s16x8*)&Ah[kb][wm * 64 + mi * 32 + r][0];
                const s16x8 al = *(const s16x8*)&Al[kb][wm * 64 + mi * 32 + r][0];
                accr[mi] = __builtin_amdgcn_mfma_f32_32x32x16_bf16(ah, bh0, accr[mi], 0, 0, 0);
                accr[mi] = __builtin_amdgcn_mfma_f32_32x32x16_bf16(al, bh0, accr[mi], 0, 0, 0);
                accr[mi] = __builtin_amdgcn_mfma_f32_32x32x16_bf16(ah, bl0, accr[mi], 0, 0, 0);
                acci[mi] = __builtin_amdgcn_mfma_f32_32x32x16_bf16(ah, bh1, acci[mi], 0, 0, 0);
                acci[mi] = __builtin_amdgcn_mfma_f32_32x32x16_bf16(al, bh1, acci[mi], 0, 0, 0);
                acci[mi] = __builtin_amdgcn_mfma_f32_32x32x16_bf16(ah, bl1, acci[mi], 0, 0, 0);
            }
        }
    }

    const int col = bn + wn * 32 + (lane & 31);
    const int pc  = invp[col];
#pragma unroll
    for (int mi = 0; mi < 2; ++mi) {
#pragma unroll
        for (int reg = 0; reg < 16; ++reg) {
            const int rl   = (reg & 3) + 8 * (reg >> 2) + 4 * (lane >> 5);
            const int grow = bm + wm * 64 + mi * 32 + rl;
            const size_t o = (size_t)grow * DIM + pc;
            ushort h, l;
            split2(accr[mi][reg], h, l);
            Srh[o] = h; Srl[o] = l;
            split2(acci[mi][reg], h, l);
            Sih[o] = h; Sil[o] = l;
        }
    }
#undef S1_LOAD
}

__global__ __launch_bounds__(256, 2) void stage2_fb(
    const ushort* __restrict__ Srh, const ushort* __restrict__ Srl,
    const ushort* __restrict__ Sih, const ushort* __restrict__ Sil,
    const float* __restrict__ U1re, const float* __restrict__ U1im,
    float* __restrict__ Out) {
    __shared__ short Arh[4][128][8], Arl[4][128][8];
    __shared__ short Aih[4][128][8], Ail[4][128][8];
    __shared__ short Bh0[4][64][8], Bl0[4][64][8];
    __shared__ short Bh1[4][64][8], Bl1[4][64][8];

    const int t = threadIdx.x;
    const int lane = t & 63;
    const int w = t >> 6;
    const int wm = w >> 1, wn = w & 1;
    const int bn = blockIdx.x * 64;
    const int bm = blockIdx.y * 128;

    uint4 pRh[2], pRl[2], pIh[2], pIl[2];
    float4 pBr[2], pBi[2];

#define S2_LOAD(k0)                                                         \
    {                                                                       \
        _Pragma("unroll") for (int j = 0; j < 2; ++j) {                     \
            const int ch = j * 256 + t;                                     \
            const int ar = ch >> 2, akb = ch & 3;                           \
            const size_t ga = (size_t)(bm + ar) * DIM + (k0) + akb * 8;     \
            pRh[j] = *(const uint4*)(Srh + ga);                             \
            pRl[j] = *(const uint4*)(Srl + ga);                             \
            pIh[j] = *(const uint4*)(Sih + ga);                             \
            pIl[j] = *(const uint4*)(Sil + ga);                             \
            const int br = ch >> 3, fc = ch & 7;                            \
            const size_t gb = (size_t)(bn + br) * DIM + (k0) + fc * 4;      \
            pBr[j] = *(const float4*)(U1re + gb);                           \
            pBi[j] = *(const float4*)(U1im + gb);                           \
        }                                                                   \
    }

    f32x16 accr[2], acci[2];
#pragma unroll
    for (int mi = 0; mi < 2; ++mi)
#pragma unroll
        for (int e = 0; e < 16; ++e) { accr[mi][e] = 0.f; acci[mi][e] = 0.f; }

    S2_LOAD(0);

    for (int k0 = 0; k0 < DIM; k0 += 32) {
        __syncthreads();
#pragma unroll
        for (int j = 0; j < 2; ++j) {
            const int ch = j * 256 + t;
            const int ar = ch >> 2, akb = ch & 3;
            *(uint4*)&Arh[akb][ar][0] = pRh[j];
            *(uint4*)&Arl[akb][ar][0] = pRl[j];
            *(uint4*)&Aih[akb][ar][0] = pIh[j];
            *(uint4*)&Ail[akb][ar][0] = pIl[j];
            const int br = ch >> 3, fc = ch & 7;
            const int bkb = fc >> 1, bo = (fc & 1) * 4;
            ushort h0, l0, h1, l1, h2, l2, h3, l3;
            split2(pBr[j].x, h0, l0); split2(pBr[j].y, h1, l1);
            split2(pBr[j].z, h2, l2); split2(pBr[j].w, h3, l3);
            *(uint2*)&Bh0[bkb][br][bo] = make_uint2(pack2(h0, h1), pack2(h2, h3));
            *(uint2*)&Bl0[bkb][br][bo] = make_uint2(pack2(l0, l1), pack2(l2, l3));
            split2(pBi[j].x, h0, l0); split2(pBi[j].y, h1, l1);
            split2(pBi[j].z, h2, l2); split2(pBi[j].w, h3, l3);
            *(uint2*)&Bh1[bkb][br][bo] = make_uint2(pack2(h0, h1), pack2(h2, h3));
            *(uint2*)&Bl1[bkb][br][bo] = make_uint2(pack2(l0, l1), pack2(l2, l3));
        }
        __syncthreads();
        if (k0 + 32 < DIM) S2_LOAD(k0 + 32);

#pragma unroll
        for (int ks = 0; ks < 2; ++ks) {
            const int kb = ks * 2 + (lane >> 5);
            const int r  = lane & 31;
            const s16x8 urh = *(const s16x8*)&Bh0[kb][wn * 32 + r][0];
            const s16x8 url = *(const s16x8*)&Bl0[kb][wn * 32 + r][0];
            const s16x8 uih = *(const s16x8*)&Bh1[kb][wn * 32 + r][0];
            const s16x8 uil = *(const s16x8*)&Bl1[kb][wn * 32 + r][0];
            const s16x8 nuih = uih ^ (short)0x8000;
            const s16x8 nuil = uil ^ (short)0x8000;
#pragma unroll
            for (int mi = 0; mi < 2; ++mi) {
                const int arow = wm * 64 + mi * 32 + r;
                const s16x8 srh = *(const s16x8*)&Arh[kb][arow][0];
                const s16x8 srl = *(const s16x8*)&Arl[kb][arow][0];
                const s16x8 sih = *(const s16x8*)&Aih[kb][arow][0];
                const s16x8 sil = *(const s16x8*)&Ail[kb][arow][0];
                accr[mi] = __builtin_amdgcn_mfma_f32_32x32x16_bf16(srh, urh,  accr[mi], 0, 0, 0);
                accr[mi] = __builtin_amdgcn_mfma_f32_32x32x16_bf16(srl, urh,  accr[mi], 0, 0, 0);
                accr[mi] = __builtin_amdgcn_mfma_f32_32x32x16_bf16(srh, url,  accr[mi], 0, 0, 0);
                accr[mi] = __builtin_amdgcn_mfma_f32_32x32x16_bf16(sih, nuih, accr[mi], 0, 0, 0);
                accr[mi] = __builtin_amdgcn_mfma_f32_32x32x16_bf16(sil, nuih, accr[mi], 0, 0, 0);
                accr[mi] = __builtin_amdgcn_mfma_f32_32x32x16_bf16(sih, nuil, accr[mi], 0, 0, 0);
                acci[mi] = __builtin_amdgcn_mfma_f32_32x32x16_bf16(srh, uih,  acci[mi], 0, 0, 0);
                acci[mi] = __builtin_amdgcn_mfma_f32_32x32x16_bf16(srl, uih,  acci[mi], 0, 0, 0);
                acci[mi] = __builtin_amdgcn_mfma_f32_32x32x16_bf16(srh, uil,  acci[mi], 0, 0, 0);
                acci[mi] = __builtin_amdgcn_mfma_f32_32x32x16_bf16(sih, urh,  acci[mi], 0, 0, 0);
                acci[mi] = __builtin_amdgcn_mfma_f32_32x32x16_bf16(sil, urh,  acci[mi], 0, 0, 0);
                acci[mi] = __builtin_amdgcn_mfma_f32_32x32x16_bf16(sih, url,  acci[mi], 0, 0, 0);
            }
        }
    }

    const int col = bn + wn * 32 + (lane & 31);
#pragma unroll
    for (int mi = 0; mi < 2; ++mi) {
#pragma unroll
        for (int reg = 0; reg < 16; ++reg) {
            const int rl   = (reg & 3) + 8 * (reg >> 2) + 4 * (lane >> 5);
            const int grow = bm + wm * 64 + mi * 32 + rl;
            const float vr = accr[mi][reg], vi = acci[mi][reg];
            Out[(size_t)grow * DIM + col] = sqrtf(vr * vr + vi * vi);
        }
    }
#undef S2_LOAD
}

// ---------------------------------------------------------------------------
extern "C" void kernel_launch(void* const* d_in, const int* in_sizes, int n_in,
                              void* d_out, int out_size, void* d_ws, size_t ws_size,
                              hipStream_t stream) {
    const float* X    = (const float*)d_in[0];
    const float* Ure  = (const float*)d_in[1];
    const float* Uim  = (const float*)d_in[2];
    const float* U1re = (const float*)d_in[3];
    const float* U1im = (const float*)d_in[4];
    float* Out = (float*)d_out;

    char* wsp = (char*)d_ws;
    const size_t MATX = (size_t)BSZ * DIM;   // elements per state matrix
    const size_t MATU = (size_t)DIM * DIM;   // elements per U matrix
    const size_t NEED = 16384 + 6 * MATX * 2 + 8 * MATU * 2;   // ~304 MB

    int* invp = (int*)wsp;

    if (ws_size >= NEED) {
        char* p = wsp + 16384;
        ushort* Xh  = (ushort*)p; p += MATX * 2;
        ushort* Xl  = (ushort*)p; p += MATX * 2;
        ushort* Srh = (ushort*)p; p += MATX * 2;
        ushort* Srl = (ushort*)p; p += MATX * 2;
        ushort* Sih = (ushort*)p; p += MATX * 2;
        ushort* Sil = (ushort*)p; p += MATX * 2;
        ushort* Urh = (ushort*)p; p += MATU * 2;
        ushort* Url = (ushort*)p; p += MATU * 2;
        ushort* Uih = (ushort*)p; p += MATU * 2;
        ushort* Uil = (ushort*)p; p += MATU * 2;
        ushort* Vrh = (ushort*)p; p += MATU * 2;
        ushort* Vrl = (ushort*)p; p += MATU * 2;
        ushort* Vih = (ushort*)p; p += MATU * 2;
        ushort* Vil = (ushort*)p; p += MATU * 2;

        perm_kernel<<<DIM / 256, 256, 0, stream>>>(invp);
        norm_split_kernel<<<BSZ, 256, 0, stream>>>(X, Xh, Xl);
        presplit<false><<<DIM, 256, 0, stream>>>(Ure, Uim, invp, Urh, Url, Uih, Uil);
        presplit<true><<<DIM, 256, 0, stream>>>(U1re, U1im, invp, Vrh, Vrl, Vih, Vil);

        dim3 grid(BSZ / 128, DIM / 64);   // (8, 64): x = batch panel -> XCD-local S
        stage1_gl<<<grid, 256, 0, stream>>>(Xh, Xl, Urh, Url, Uih, Uil,
                                            Srh, Srl, Sih, Sil);
        stage2_gl<<<grid, 256, 0, stream>>>(Srh, Srl, Sih, Sil,
                                            Vrh, Vrl, Vih, Vil, Out);
    } else {
        // Fallback: round-1 path (48 MB workspace)
        char* p = wsp + 16384;
        ushort* Xh  = (ushort*)p; p += MATX * 2;
        ushort* Xl  = (ushort*)p; p += MATX * 2;
        ushort* Srh = (ushort*)p; p += MATX * 2;
        ushort* Srl = (ushort*)p; p += MATX * 2;
        ushort* Sih = (ushort*)p; p += MATX * 2;
        ushort* Sil = (ushort*)p; p += MATX * 2;

        perm_kernel<<<DIM / 256, 256, 0, stream>>>(invp);
        norm_split_kernel<<<BSZ, 256, 0, stream>>>(X, Xh, Xl);

        dim3 grid(DIM / 64, BSZ / 128);
        stage1_fb<<<grid, 256, 0, stream>>>(Xh, Xl, Ure, Uim, invp,
                                            Srh, Srl, Sih, Sil);
        stage2_fb<<<grid, 256, 0, stream>>>(Srh, Srl, Sih, Sil, U1re, U1im, Out);
    }
}